// Round 3
// baseline (138.969 us; speedup 1.0000x reference)
//
#include <hip/hip_runtime.h>

#define S_DIM 16
#define B_DIM 512
#define H_DIM 2048
#define EPS 1e-8f

typedef short bf16x8 __attribute__((ext_vector_type(8)));
typedef float f32x4 __attribute__((ext_vector_type(4)));

__device__ __forceinline__ unsigned short f2bf(float f) {
    union { float f; unsigned int u; } v; v.f = f;
    unsigned int u = v.u;
    unsigned int r = (u + 0x7fffu + ((u >> 16) & 1u)) >> 16;
    return (unsigned short)r;
}

__device__ __forceinline__ float dot4(const float4& a, const float4& b) {
    return a.x*b.x + a.y*b.y + a.z*b.z + a.w*b.w;
}

// ---------------- Kernel 1: sims + weighted mean -> wRep (bf16) ----------------
// grid: B_DIM blocks x 512 threads (8 waves). Wave w handles s = w and s = w+8,
// sequentially, accumulating sim*e into registers. OG row lives in LDS (shared
// by all waves). E read exactly once, fully coalesced (1 KiB per b128 per wave).
// Live VGPRs ~85 (e[8]=32, acc[8]=32, temps) -> fits 128 @ 4 waves/SIMD.
__global__ __launch_bounds__(512, 4) void simwrep_kernel(
    const float* __restrict__ OG, const float* __restrict__ E,
    unsigned short* __restrict__ wrep) {
    const int b = blockIdx.x;
    const int t = threadIdx.x;
    const int lane = t & 63;
    const int wave = t >> 6;

    __shared__ float4 ogs[512];      // 8 KiB: the OG row
    __shared__ float4 buf[8][512];   // 64 KiB: per-wave partials
    __shared__ float red[8];

    // Cooperative OG load + ||og||^2 block reduction
    const float4* og4 = (const float4*)(OG + (size_t)b * H_DIM);
    float4 o = og4[t];
    ogs[t] = o;
    float p = dot4(o, o);
    #pragma unroll
    for (int m = 32; m >= 1; m >>= 1) p += __shfl_xor(p, m, 64);
    if (lane == 0) red[wave] = p;
    __syncthreads();
    float og2 = 0.f;
    #pragma unroll
    for (int w = 0; w < 8; ++w) og2 += red[w];
    const float onorm = sqrtf(og2);

    float4 acc[8];
    #pragma unroll
    for (int i = 0; i < 8; ++i) acc[i] = make_float4(0.f, 0.f, 0.f, 0.f);

    #pragma unroll
    for (int si = 0; si < 2; ++si) {
        const int s = wave + si * 8;
        const float4* e4 = (const float4*)(E + ((size_t)s * B_DIM + b) * H_DIM);
        float4 e[8];
        float d = 0.f, n = 0.f;
        #pragma unroll
        for (int i = 0; i < 8; ++i) {
            e[i] = e4[i * 64 + lane];
            float4 og = ogs[i * 64 + lane];
            d += dot4(e[i], og);
            n += dot4(e[i], e[i]);
        }
        #pragma unroll
        for (int m = 32; m >= 1; m >>= 1) {
            d += __shfl_xor(d, m, 64);
            n += __shfl_xor(n, m, 64);
        }
        const float sim = d / fmaxf(sqrtf(n) * onorm, EPS);
        #pragma unroll
        for (int i = 0; i < 8; ++i) {
            acc[i].x += e[i].x * sim; acc[i].y += e[i].y * sim;
            acc[i].z += e[i].z * sim; acc[i].w += e[i].w * sim;
        }
    }

    #pragma unroll
    for (int i = 0; i < 8; ++i) buf[wave][i * 64 + lane] = acc[i];
    __syncthreads();

    // thread t combines the 8 wave partials for float4-chunk t, mean, bf16
    float4 s = buf[0][t];
    #pragma unroll
    for (int w = 1; w < 8; ++w) {
        float4 v = buf[w][t];
        s.x += v.x; s.y += v.y; s.z += v.z; s.w += v.w;
    }
    const float sc = 1.f / (float)S_DIM;
    ushort4 ob;
    ob.x = f2bf(s.x * sc); ob.y = f2bf(s.y * sc);
    ob.z = f2bf(s.z * sc); ob.w = f2bf(s.w * sc);
    ((ushort4*)wrep)[(size_t)b * (H_DIM / 4) + t] = ob;
}

// ---------------- Kernel 2: out = wRep @ W^T + b  (bf16 MFMA, fp32 acc) ----------------
// A: 512x2048 bf16 K-contig. W: 2048x2048 fp32 (row n = out col n, K-contig),
// converted to bf16 during LDS staging. 64x64 tile, BK=64 (32 iters), 4 waves
// each 32x32 via 2x2x2 of 16x16x32. 256 blocks = 1/CU. Register prefetch.
__global__ __launch_bounds__(256) void gemm_kernel(
    const unsigned short* __restrict__ A, const float* __restrict__ W,
    const float* __restrict__ bias, float* __restrict__ out) {
    const int n0 = blockIdx.x * 64;
    const int m0 = blockIdx.y * 64;

    __shared__ unsigned short As[64][72];  // 64 k + 8 pad
    __shared__ unsigned short Ws[64][72];

    const int t = threadIdx.x;
    const int lane = t & 63;
    const int wave = t >> 6;
    const int wm = (wave & 1) * 32;
    const int wn = (wave >> 1) * 32;
    const int lr = t >> 2;   // staging row 0..63
    const int lq = t & 3;    // 16-short chunk within the row

    const unsigned short* ap = A + (size_t)(m0 + lr) * H_DIM + lq * 16;
    const float* wp = W + (size_t)(n0 + lr) * H_DIM + lq * 16;

    f32x4 acc00 = {0.f, 0.f, 0.f, 0.f};
    f32x4 acc01 = {0.f, 0.f, 0.f, 0.f};
    f32x4 acc10 = {0.f, 0.f, 0.f, 0.f};
    f32x4 acc11 = {0.f, 0.f, 0.f, 0.f};

    const int row = lane & 15;
    const int q = lane >> 4;

    uint4 av0 = *(const uint4*)(ap);
    uint4 av1 = *(const uint4*)(ap + 8);
    float4 wv0 = *(const float4*)(wp);
    float4 wv1 = *(const float4*)(wp + 4);
    float4 wv2 = *(const float4*)(wp + 8);
    float4 wv3 = *(const float4*)(wp + 12);

    for (int k0 = 0; k0 < H_DIM; k0 += 64) {
        *(uint4*)&As[lr][lq * 16] = av0;
        *(uint4*)&As[lr][lq * 16 + 8] = av1;
        ushort4 c0, c1, c2, c3;
        c0.x = f2bf(wv0.x); c0.y = f2bf(wv0.y); c0.z = f2bf(wv0.z); c0.w = f2bf(wv0.w);
        c1.x = f2bf(wv1.x); c1.y = f2bf(wv1.y); c1.z = f2bf(wv1.z); c1.w = f2bf(wv1.w);
        c2.x = f2bf(wv2.x); c2.y = f2bf(wv2.y); c2.z = f2bf(wv2.z); c2.w = f2bf(wv2.w);
        c3.x = f2bf(wv3.x); c3.y = f2bf(wv3.y); c3.z = f2bf(wv3.z); c3.w = f2bf(wv3.w);
        *(ushort4*)&Ws[lr][lq * 16]      = c0;
        *(ushort4*)&Ws[lr][lq * 16 + 4]  = c1;
        *(ushort4*)&Ws[lr][lq * 16 + 8]  = c2;
        *(ushort4*)&Ws[lr][lq * 16 + 12] = c3;
        __syncthreads();
        if (k0 + 64 < H_DIM) {  // register prefetch of next tiles
            av0 = *(const uint4*)(ap + k0 + 64);
            av1 = *(const uint4*)(ap + k0 + 72);
            wv0 = *(const float4*)(wp + k0 + 64);
            wv1 = *(const float4*)(wp + k0 + 68);
            wv2 = *(const float4*)(wp + k0 + 72);
            wv3 = *(const float4*)(wp + k0 + 76);
        }
        #pragma unroll
        for (int ks = 0; ks < 2; ++ks) {
            bf16x8 a0 = *(const bf16x8*)&As[wm + row][ks * 32 + q * 8];
            bf16x8 a1 = *(const bf16x8*)&As[wm + 16 + row][ks * 32 + q * 8];
            bf16x8 b0 = *(const bf16x8*)&Ws[wn + row][ks * 32 + q * 8];
            bf16x8 b1 = *(const bf16x8*)&Ws[wn + 16 + row][ks * 32 + q * 8];
            acc00 = __builtin_amdgcn_mfma_f32_16x16x32_bf16(a0, b0, acc00, 0, 0, 0);
            acc01 = __builtin_amdgcn_mfma_f32_16x16x32_bf16(a0, b1, acc01, 0, 0, 0);
            acc10 = __builtin_amdgcn_mfma_f32_16x16x32_bf16(a1, b0, acc10, 0, 0, 0);
            acc11 = __builtin_amdgcn_mfma_f32_16x16x32_bf16(a1, b1, acc11, 0, 0, 0);
        }
        __syncthreads();
    }

    // D mapping: col=lane&15, row=(lane>>4)*4+reg
    const int col = lane & 15;
    const float bias0 = bias[n0 + wn + col];
    const float bias1 = bias[n0 + wn + 16 + col];
    #pragma unroll
    for (int r = 0; r < 4; ++r) {
        const int mr = q * 4 + r;
        float* o0 = out + (size_t)(m0 + wm + mr) * H_DIM + n0 + wn;
        float* o1 = out + (size_t)(m0 + wm + 16 + mr) * H_DIM + n0 + wn;
        o0[col]      = acc00[r] + bias0;
        o0[16 + col] = acc01[r] + bias1;
        o1[col]      = acc10[r] + bias0;
        o1[16 + col] = acc11[r] + bias1;
    }
}

extern "C" void kernel_launch(void* const* d_in, const int* in_sizes, int n_in,
                              void* d_out, int out_size, void* d_ws, size_t ws_size,
                              hipStream_t stream) {
    const float* OG   = (const float*)d_in[0];
    const float* E    = (const float*)d_in[1];
    const float* W    = (const float*)d_in[2];
    const float* bias = (const float*)d_in[3];
    float* out = (float*)d_out;

    unsigned short* wrep = (unsigned short*)d_ws;  // 512*2048 bf16 = 2 MiB

    simwrep_kernel<<<B_DIM, 512, 0, stream>>>(OG, E, wrep);
    gemm_kernel<<<dim3(H_DIM / 64, B_DIM / 64), 256, 0, stream>>>(wrep, W, bias, out);
}

// Round 4
// 128.580 us; speedup vs baseline: 1.0808x; 1.0808x over previous
//
#include <hip/hip_runtime.h>

#define S_DIM 16
#define B_DIM 512
#define H_DIM 2048
#define EPS 1e-8f

typedef short bf16x8 __attribute__((ext_vector_type(8)));
typedef float f32x4 __attribute__((ext_vector_type(4)));

__device__ __forceinline__ unsigned short f2bf(float f) {
    union { float f; unsigned int u; } v; v.f = f;
    unsigned int u = v.u;
    unsigned int r = (u + 0x7fffu + ((u >> 16) & 1u)) >> 16;
    return (unsigned short)r;
}

__device__ __forceinline__ float dot4(const float4& a, const float4& b) {
    return a.x*b.x + a.y*b.y + a.z*b.z + a.w*b.w;
}

// ---------------- Kernel 1: sims + weighted mean -> wRep (bf16), fused W->bf16 ----------------
// grid: B_DIM blocks x 512 threads (8 waves). Wave w handles s = w and s = w+8
// sequentially; sim*e accumulates into this wave's LDS buffer (only e[8] live in
// VGPRs -> no spill). OG row in LDS, shared by all waves. E read exactly once.
// Tail: each block converts 32 KiB of W to bf16 (W-convert rides the idle VALU
// of this HBM-bound kernel; removes the separate convert launch).
__global__ __launch_bounds__(512) void simwrep_kernel(
    const float* __restrict__ OG, const float* __restrict__ E,
    const float* __restrict__ W, unsigned short* __restrict__ wrep,
    unsigned short* __restrict__ Wb) {
    const int b = blockIdx.x;
    const int t = threadIdx.x;
    const int lane = t & 63;
    const int wave = t >> 6;

    __shared__ float4 ogs[512];      // 8 KiB: the OG row
    __shared__ float4 buf[8][512];   // 64 KiB: per-wave partials
    __shared__ float red[8];

    // Cooperative OG load + ||og||^2 block reduction
    const float4* og4 = (const float4*)(OG + (size_t)b * H_DIM);
    float4 o = og4[t];
    ogs[t] = o;
    float p = dot4(o, o);
    #pragma unroll
    for (int m = 32; m >= 1; m >>= 1) p += __shfl_xor(p, m, 64);
    if (lane == 0) red[wave] = p;
    __syncthreads();
    float og2 = 0.f;
    #pragma unroll
    for (int w = 0; w < 8; ++w) og2 += red[w];
    const float onorm = sqrtf(og2);

    #pragma unroll
    for (int si = 0; si < 2; ++si) {
        const int s = wave + si * 8;
        const float4* e4 = (const float4*)(E + ((size_t)s * B_DIM + b) * H_DIM);
        float4 e[8];
        float d = 0.f, n = 0.f;
        #pragma unroll
        for (int i = 0; i < 8; ++i) {
            e[i] = e4[i * 64 + lane];
            float4 og = ogs[i * 64 + lane];
            d += dot4(e[i], og);
            n += dot4(e[i], e[i]);
        }
        #pragma unroll
        for (int m = 32; m >= 1; m >>= 1) {
            d += __shfl_xor(d, m, 64);
            n += __shfl_xor(n, m, 64);
        }
        const float sim = d / fmaxf(sqrtf(n) * onorm, EPS);
        if (si == 0) {
            #pragma unroll
            for (int i = 0; i < 8; ++i) {
                float4 v;
                v.x = e[i].x * sim; v.y = e[i].y * sim;
                v.z = e[i].z * sim; v.w = e[i].w * sim;
                buf[wave][i * 64 + lane] = v;
            }
        } else {
            #pragma unroll
            for (int i = 0; i < 8; ++i) {
                float4 v = buf[wave][i * 64 + lane];
                v.x += e[i].x * sim; v.y += e[i].y * sim;
                v.z += e[i].z * sim; v.w += e[i].w * sim;
                buf[wave][i * 64 + lane] = v;
            }
        }
    }
    __syncthreads();

    // thread t combines the 8 wave partials for float4-chunk t, mean, bf16
    float4 s = buf[0][t];
    #pragma unroll
    for (int w = 1; w < 8; ++w) {
        float4 v = buf[w][t];
        s.x += v.x; s.y += v.y; s.z += v.z; s.w += v.w;
    }
    const float sc = 1.f / (float)S_DIM;
    ushort4 ob;
    ob.x = f2bf(s.x * sc); ob.y = f2bf(s.y * sc);
    ob.z = f2bf(s.z * sc); ob.w = f2bf(s.w * sc);
    ((ushort4*)wrep)[(size_t)b * (H_DIM / 4) + t] = ob;

    // Fused W -> bf16 tail: block b converts float4-indices [b*2048, (b+1)*2048)
    const float4* w4 = (const float4*)W;
    #pragma unroll
    for (int j = 0; j < 4; ++j) {
        const size_t idx = (size_t)b * 2048 + j * 512 + t;
        float4 v = w4[idx];
        ushort4 c;
        c.x = f2bf(v.x); c.y = f2bf(v.y); c.z = f2bf(v.z); c.w = f2bf(v.w);
        ((ushort4*)Wb)[idx] = c;
    }
}

// ---------------- Kernel 2: out = wRep @ Wb^T + b  (bf16 MFMA, fp32 acc) ----------------
// A: 512x2048 bf16 K-contig. Wb: 2048x2048 bf16 (row n = out col n, K-contig).
// 64x64 tile, BK=64 (32 iters), 4 waves each 32x32 via 2x2x2 of 16x16x32.
// 256 blocks = 1/CU. Register prefetch across the barrier.
__global__ __launch_bounds__(256) void gemm_kernel(
    const unsigned short* __restrict__ A, const unsigned short* __restrict__ Wb,
    const float* __restrict__ bias, float* __restrict__ out) {
    const int n0 = blockIdx.x * 64;
    const int m0 = blockIdx.y * 64;

    __shared__ unsigned short As[64][72];  // 64 k + 8 pad (row = 144 B, 16B-aligned)
    __shared__ unsigned short Ws[64][72];

    const int t = threadIdx.x;
    const int lane = t & 63;
    const int wave = t >> 6;
    const int wm = (wave & 1) * 32;
    const int wn = (wave >> 1) * 32;
    const int lr = t >> 2;   // staging row 0..63
    const int lq = t & 3;    // 16-elem chunk within the row

    const unsigned short* ap = A + (size_t)(m0 + lr) * H_DIM + lq * 16;
    const unsigned short* bp = Wb + (size_t)(n0 + lr) * H_DIM + lq * 16;

    f32x4 acc00 = {0.f, 0.f, 0.f, 0.f};
    f32x4 acc01 = {0.f, 0.f, 0.f, 0.f};
    f32x4 acc10 = {0.f, 0.f, 0.f, 0.f};
    f32x4 acc11 = {0.f, 0.f, 0.f, 0.f};

    const int row = lane & 15;
    const int q = lane >> 4;

    uint4 av0 = *(const uint4*)(ap);
    uint4 av1 = *(const uint4*)(ap + 8);
    uint4 bv0 = *(const uint4*)(bp);
    uint4 bv1 = *(const uint4*)(bp + 8);

    for (int k0 = 0; k0 < H_DIM; k0 += 64) {
        *(uint4*)&As[lr][lq * 16]     = av0;
        *(uint4*)&As[lr][lq * 16 + 8] = av1;
        *(uint4*)&Ws[lr][lq * 16]     = bv0;
        *(uint4*)&Ws[lr][lq * 16 + 8] = bv1;
        __syncthreads();
        if (k0 + 64 < H_DIM) {  // register prefetch of next tiles
            av0 = *(const uint4*)(ap + k0 + 64);
            av1 = *(const uint4*)(ap + k0 + 72);
            bv0 = *(const uint4*)(bp + k0 + 64);
            bv1 = *(const uint4*)(bp + k0 + 72);
        }
        #pragma unroll
        for (int ks = 0; ks < 2; ++ks) {
            bf16x8 a0 = *(const bf16x8*)&As[wm + row][ks * 32 + q * 8];
            bf16x8 a1 = *(const bf16x8*)&As[wm + 16 + row][ks * 32 + q * 8];
            bf16x8 b0 = *(const bf16x8*)&Ws[wn + row][ks * 32 + q * 8];
            bf16x8 b1 = *(const bf16x8*)&Ws[wn + 16 + row][ks * 32 + q * 8];
            acc00 = __builtin_amdgcn_mfma_f32_16x16x32_bf16(a0, b0, acc00, 0, 0, 0);
            acc01 = __builtin_amdgcn_mfma_f32_16x16x32_bf16(a0, b1, acc01, 0, 0, 0);
            acc10 = __builtin_amdgcn_mfma_f32_16x16x32_bf16(a1, b0, acc10, 0, 0, 0);
            acc11 = __builtin_amdgcn_mfma_f32_16x16x32_bf16(a1, b1, acc11, 0, 0, 0);
        }
        __syncthreads();
    }

    // D mapping: col=lane&15, row=(lane>>4)*4+reg
    const int col = lane & 15;
    const float bias0 = bias[n0 + wn + col];
    const float bias1 = bias[n0 + wn + 16 + col];
    #pragma unroll
    for (int r = 0; r < 4; ++r) {
        const int mr = q * 4 + r;
        float* o0 = out + (size_t)(m0 + wm + mr) * H_DIM + n0 + wn;
        float* o1 = out + (size_t)(m0 + wm + 16 + mr) * H_DIM + n0 + wn;
        o0[col]      = acc00[r] + bias0;
        o0[16 + col] = acc01[r] + bias1;
        o1[col]      = acc10[r] + bias0;
        o1[16 + col] = acc11[r] + bias1;
    }
}

extern "C" void kernel_launch(void* const* d_in, const int* in_sizes, int n_in,
                              void* d_out, int out_size, void* d_ws, size_t ws_size,
                              hipStream_t stream) {
    const float* OG   = (const float*)d_in[0];
    const float* E    = (const float*)d_in[1];
    const float* W    = (const float*)d_in[2];
    const float* bias = (const float*)d_in[3];
    float* out = (float*)d_out;

    unsigned short* wrep = (unsigned short*)d_ws;                 // 512*2048 bf16 = 2 MiB
    unsigned short* Wb   = wrep + (size_t)B_DIM * H_DIM;          // 2048*2048 bf16 = 8 MiB

    simwrep_kernel<<<B_DIM, 512, 0, stream>>>(OG, E, W, wrep, Wb);
    gemm_kernel<<<dim3(H_DIM / 64, B_DIM / 64), 256, 0, stream>>>(wrep, Wb, bias, out);
}

// Round 5
// 125.472 us; speedup vs baseline: 1.1076x; 1.0248x over previous
//
#include <hip/hip_runtime.h>

#define S_DIM 16
#define B_DIM 512
#define H_DIM 2048
#define EPS 1e-8f

typedef short bf16x8 __attribute__((ext_vector_type(8)));
typedef float f32x4 __attribute__((ext_vector_type(4)));

__device__ __forceinline__ unsigned short f2bf(float f) {
    union { float f; unsigned int u; } v; v.f = f;
    unsigned int u = v.u;
    unsigned int r = (u + 0x7fffu + ((u >> 16) & 1u)) >> 16;
    return (unsigned short)r;
}

__device__ __forceinline__ float dot4(const float4& a, const float4& b) {
    return a.x*b.x + a.y*b.y + a.z*b.z + a.w*b.w;
}

// ---------------- Kernel 1: sims + weighted mean -> wRep (bf16), fused W->bf16 ----------------
// grid: B_DIM blocks x 512 threads (8 waves), 2 blocks/CU (72 KiB LDS, <=128 VGPR).
// Wave w loads BOTH its rows (s=w, s=w+8) up front -> 16 b128 loads in flight,
// one fused shuffle-reduction, one LDS accumulate. OG row in LDS (shared).
// E read exactly once, fully coalesced. Tail: 32 KiB/block of W -> bf16.
__global__ __launch_bounds__(512, 4) void simwrep_kernel(
    const float* __restrict__ OG, const float* __restrict__ E,
    const float* __restrict__ W, unsigned short* __restrict__ wrep,
    unsigned short* __restrict__ Wb) {
    const int b = blockIdx.x;
    const int t = threadIdx.x;
    const int lane = t & 63;
    const int wave = t >> 6;

    __shared__ float4 ogs[512];      // 8 KiB
    __shared__ float4 buf[8][512];   // 64 KiB
    __shared__ float red[8];

    // Cooperative OG load + ||og||^2 block reduction
    const float4* og4 = (const float4*)(OG + (size_t)b * H_DIM);
    float4 o = og4[t];
    ogs[t] = o;
    float p = dot4(o, o);
    #pragma unroll
    for (int m = 32; m >= 1; m >>= 1) p += __shfl_xor(p, m, 64);
    if (lane == 0) red[wave] = p;
    __syncthreads();
    float og2 = 0.f;
    #pragma unroll
    for (int w = 0; w < 8; ++w) og2 += red[w];
    const float onorm = sqrtf(og2);

    // Dual-row load: s = wave and s = wave+8
    const float4* e4a = (const float4*)(E + ((size_t)wave * B_DIM + b) * H_DIM);
    const float4* e4b = (const float4*)(E + ((size_t)(wave + 8) * B_DIM + b) * H_DIM);
    float4 ea[8], eb[8];
    #pragma unroll
    for (int i = 0; i < 8; ++i) {
        ea[i] = e4a[i * 64 + lane];
        eb[i] = e4b[i * 64 + lane];
    }
    float da = 0.f, na = 0.f, db = 0.f, nb = 0.f;
    #pragma unroll
    for (int i = 0; i < 8; ++i) {
        float4 og = ogs[i * 64 + lane];
        da += dot4(ea[i], og);
        na += dot4(ea[i], ea[i]);
        db += dot4(eb[i], og);
        nb += dot4(eb[i], eb[i]);
    }
    #pragma unroll
    for (int m = 32; m >= 1; m >>= 1) {
        da += __shfl_xor(da, m, 64);
        na += __shfl_xor(na, m, 64);
        db += __shfl_xor(db, m, 64);
        nb += __shfl_xor(nb, m, 64);
    }
    const float sima = da / fmaxf(sqrtf(na) * onorm, EPS);
    const float simb = db / fmaxf(sqrtf(nb) * onorm, EPS);

    #pragma unroll
    for (int i = 0; i < 8; ++i) {
        float4 v;
        v.x = ea[i].x * sima + eb[i].x * simb;
        v.y = ea[i].y * sima + eb[i].y * simb;
        v.z = ea[i].z * sima + eb[i].z * simb;
        v.w = ea[i].w * sima + eb[i].w * simb;
        buf[wave][i * 64 + lane] = v;
    }
    __syncthreads();

    // thread t combines the 8 wave partials for float4-chunk t, mean, bf16
    float4 s = buf[0][t];
    #pragma unroll
    for (int w = 1; w < 8; ++w) {
        float4 v = buf[w][t];
        s.x += v.x; s.y += v.y; s.z += v.z; s.w += v.w;
    }
    const float sc = 1.f / (float)S_DIM;
    ushort4 ob;
    ob.x = f2bf(s.x * sc); ob.y = f2bf(s.y * sc);
    ob.z = f2bf(s.z * sc); ob.w = f2bf(s.w * sc);
    ((ushort4*)wrep)[(size_t)b * (H_DIM / 4) + t] = ob;

    // Fused W -> bf16 tail: block b converts float4-indices [b*2048, (b+1)*2048)
    const float4* w4 = (const float4*)W;
    #pragma unroll
    for (int j = 0; j < 4; ++j) {
        const size_t idx = (size_t)b * 2048 + j * 512 + t;
        float4 v = w4[idx];
        ushort4 c;
        c.x = f2bf(v.x); c.y = f2bf(v.y); c.z = f2bf(v.z); c.w = f2bf(v.w);
        ((ushort4*)Wb)[idx] = c;
    }
}

// ---------------- Kernel 2: out = wRep @ Wb^T + b  (bf16 MFMA, fp32 acc) ----------------
// 64(M)x32(N) tiles -> grid 512 = 2 blocks/CU so one block's compute overlaps the
// other's barrier drain. BK=64 (32 iters). 4 waves: wm=(w&1)*32, wn=(w>>1)*16;
// each wave 32x16 via 2 accs of 16x16x32. Register prefetch across the barrier.
__global__ __launch_bounds__(256) void gemm_kernel(
    const unsigned short* __restrict__ A, const unsigned short* __restrict__ Wb,
    const float* __restrict__ bias, float* __restrict__ out) {
    const int n0 = blockIdx.x * 32;
    const int m0 = blockIdx.y * 64;

    __shared__ unsigned short As[64][72];  // 9 KiB (+8 pad)
    __shared__ unsigned short Ws[32][72];  // 4.5 KiB

    const int t = threadIdx.x;
    const int lane = t & 63;
    const int wave = t >> 6;
    const int wm = (wave & 1) * 32;
    const int wn = (wave >> 1) * 16;

    const int lrA = t >> 2, lqA = t & 3;   // A: 4 thr/row, 32 shorts each
    const int lrB = t >> 3, lqB = t & 7;   // Ws: 8 thr/row, 8 shorts each

    const unsigned short* ap = A + (size_t)(m0 + lrA) * H_DIM + lqA * 16;
    const unsigned short* bp = Wb + (size_t)(n0 + lrB) * H_DIM + lqB * 8;

    f32x4 acc0 = {0.f, 0.f, 0.f, 0.f};
    f32x4 acc1 = {0.f, 0.f, 0.f, 0.f};

    const int row = lane & 15;
    const int q = lane >> 4;

    uint4 av0 = *(const uint4*)(ap);
    uint4 av1 = *(const uint4*)(ap + 8);
    uint4 bv  = *(const uint4*)(bp);

    for (int k0 = 0; k0 < H_DIM; k0 += 64) {
        *(uint4*)&As[lrA][lqA * 16]     = av0;
        *(uint4*)&As[lrA][lqA * 16 + 8] = av1;
        *(uint4*)&Ws[lrB][lqB * 8]      = bv;
        __syncthreads();
        if (k0 + 64 < H_DIM) {  // register prefetch of next tiles
            av0 = *(const uint4*)(ap + k0 + 64);
            av1 = *(const uint4*)(ap + k0 + 72);
            bv  = *(const uint4*)(bp + k0 + 64);
        }
        #pragma unroll
        for (int ks = 0; ks < 2; ++ks) {
            bf16x8 a0 = *(const bf16x8*)&As[wm + row][ks * 32 + q * 8];
            bf16x8 a1 = *(const bf16x8*)&As[wm + 16 + row][ks * 32 + q * 8];
            bf16x8 b0 = *(const bf16x8*)&Ws[wn + row][ks * 32 + q * 8];
            acc0 = __builtin_amdgcn_mfma_f32_16x16x32_bf16(a0, b0, acc0, 0, 0, 0);
            acc1 = __builtin_amdgcn_mfma_f32_16x16x32_bf16(a1, b0, acc1, 0, 0, 0);
        }
        __syncthreads();
    }

    // D mapping: col=lane&15, row=(lane>>4)*4+reg
    const int col = lane & 15;
    const float bias0 = bias[n0 + wn + col];
    #pragma unroll
    for (int r = 0; r < 4; ++r) {
        const int mr = q * 4 + r;
        float* o0 = out + (size_t)(m0 + wm + mr) * H_DIM + n0 + wn;
        float* o1 = out + (size_t)(m0 + wm + 16 + mr) * H_DIM + n0 + wn;
        o0[col] = acc0[r] + bias0;
        o1[col] = acc1[r] + bias0;
    }
}

extern "C" void kernel_launch(void* const* d_in, const int* in_sizes, int n_in,
                              void* d_out, int out_size, void* d_ws, size_t ws_size,
                              hipStream_t stream) {
    const float* OG   = (const float*)d_in[0];
    const float* E    = (const float*)d_in[1];
    const float* W    = (const float*)d_in[2];
    const float* bias = (const float*)d_in[3];
    float* out = (float*)d_out;

    unsigned short* wrep = (unsigned short*)d_ws;                 // 512*2048 bf16 = 2 MiB
    unsigned short* Wb   = wrep + (size_t)B_DIM * H_DIM;          // 2048*2048 bf16 = 8 MiB

    simwrep_kernel<<<B_DIM, 512, 0, stream>>>(OG, E, W, wrep, Wb);
    gemm_kernel<<<dim3(H_DIM / 32, B_DIM / 64), 256, 0, stream>>>(wrep, Wb, bias, out);
}